// Round 4
// baseline (2733.809 us; speedup 1.0000x reference)
//
#include <hip/hip_runtime.h>
#include <hip/hip_bf16.h>
#include <cstdint>
#include <cstddef>

#define N_NODES_C  100000
#define N_EDGES_C  1600000
#define N_GRAPHS_C 256
#define HID_C      128
// 1/sqrt(1+1e-5)
#define BN_SCALE_C 0.9999950000374997f

#define SCAN_B 1024
#define SCAN_NB ((N_NODES_C + SCAN_B - 1) / SCAN_B)   // 98

#define N_CHUNKS     8
#define CHUNK_NODES  (N_NODES_C / N_CHUNKS)           // 12500
#define CAP_EDGES    300000                           // >> 200K expected/chunk

struct __align__(8) bf4 { __hip_bfloat16 a, b, c, d; };

// ---------------------------------------------------------------------------
// CSR build: histogram of dst, inclusive scan, scatter edge ids.
// ---------------------------------------------------------------------------
__global__ __launch_bounds__(256) void hist_kernel(
    const int* __restrict__ dst, int* __restrict__ counts, int n_edges)
{
    int e = blockIdx.x * 256 + threadIdx.x;
    if (e < n_edges) atomicAdd(&counts[dst[e]], 1);
}

__global__ __launch_bounds__(SCAN_B) void scan1_kernel(
    const int* __restrict__ counts, int* __restrict__ incl,
    int* __restrict__ blocksums, int n)
{
    __shared__ int sdata[SCAN_B];
    const int lid = threadIdx.x;
    const int i = blockIdx.x * SCAN_B + lid;
    sdata[lid] = (i < n) ? counts[i] : 0;
    __syncthreads();
#pragma unroll
    for (int off = 1; off < SCAN_B; off <<= 1) {
        int t = (lid >= off) ? sdata[lid - off] : 0;
        __syncthreads();
        sdata[lid] += t;
        __syncthreads();
    }
    if (i < n) incl[i] = sdata[lid];
    if (lid == SCAN_B - 1) blocksums[blockIdx.x] = sdata[lid];
}

__global__ void scan2_kernel(const int* __restrict__ blocksums,
                             int* __restrict__ blockoffs, int nb)
{
    if (threadIdx.x == 0 && blockIdx.x == 0) {
        int off = 0;
        for (int b = 0; b < nb; ++b) { blockoffs[b] = off; off += blocksums[b]; }
    }
}

__global__ __launch_bounds__(SCAN_B) void scan3_kernel(
    int* __restrict__ incl, const int* __restrict__ blockoffs, int n)
{
    const int i = blockIdx.x * SCAN_B + threadIdx.x;
    if (i < n) incl[i] += blockoffs[blockIdx.x];
}

__global__ __launch_bounds__(256) void initrows_kernel(
    const int* __restrict__ incl, const int* __restrict__ counts,
    int* __restrict__ rowstart, int* __restrict__ cursor, int n)
{
    const int i = blockIdx.x * 256 + threadIdx.x;
    if (i < n) {
        const int rs = incl[i] - counts[i];
        rowstart[i] = rs;
        cursor[i]   = rs;
    }
}

__global__ __launch_bounds__(256) void scatter_kernel(
    const int* __restrict__ src, const int* __restrict__ dst,
    int* __restrict__ cursor, int* __restrict__ perm_src,
    int* __restrict__ perm_eid, int n_edges)
{
    const int e = blockIdx.x * 256 + threadIdx.x;
    if (e < n_edges) {
        const int pos = atomicAdd(&cursor[dst[e]], 1);
        perm_src[pos] = src[e];
        perm_eid[pos] = e;
    }
}

// ---------------------------------------------------------------------------
// Edge MLP (dense, streaming): for CSR edge range [e0,e1) of node chunk
// [v0,v1), compute ea_t[j - e0][f] = bf16( eb[f] + sum_k ea[j][k]*ew[k][f] ).
// Thread owns a 4-feature quad; ew quad-columns (16x float4) in registers.
// Edge gather fused via perm_eid (random 64B rows, half/quarter-wave bcast).
// ---------------------------------------------------------------------------
template<int DIN>
__global__ __launch_bounds__(256) void edge_mlp_kernel(
    const float* __restrict__ edge_attr, const int* __restrict__ perm_eid,
    const int* __restrict__ rowstart, int v0, int v1,
    const float* __restrict__ ew, const float* __restrict__ eb,
    __hip_bfloat16* __restrict__ ea_t, int n_edges)
{
    constexpr int FQ  = DIN / 4;          // feature quads: 32 (128) / 16 (64)
    constexpr int EPB = 256 / FQ;         // edge slots per block iter: 8 / 16
    const int fq = threadIdx.x & (FQ - 1);
    const int es = threadIdx.x / FQ;

    const int e0 = rowstart[v0];
    const int e1 = (v1 < N_NODES_C) ? rowstart[v1] : n_edges;
    const int e1c = min(e1, e0 + CAP_EDGES);   // never write past the buffer

    float4 ewr[16];
#pragma unroll
    for (int k = 0; k < 16; ++k)
        ewr[k] = *(const float4*)(ew + (size_t)k * DIN + fq * 4);
    const float4 ebv = *(const float4*)(eb + fq * 4);

    for (int j = e0 + blockIdx.x * EPB + es; j < e1c; j += gridDim.x * EPB) {
        const int eid = perm_eid[j];
        const float4* p = (const float4*)(edge_attr + (size_t)eid * 16);
        const float4 q0 = p[0], q1 = p[1], q2 = p[2], q3 = p[3];
        float ax = ebv.x, ay = ebv.y, az = ebv.z, aw = ebv.w;
        const float ea[16] = {q0.x, q0.y, q0.z, q0.w, q1.x, q1.y, q1.z, q1.w,
                              q2.x, q2.y, q2.z, q2.w, q3.x, q3.y, q3.z, q3.w};
#pragma unroll
        for (int k = 0; k < 16; ++k) {
            ax = fmaf(ea[k], ewr[k].x, ax);
            ay = fmaf(ea[k], ewr[k].y, ay);
            az = fmaf(ea[k], ewr[k].z, az);
            aw = fmaf(ea[k], ewr[k].w, aw);
        }
        bf4 st;
        st.a = __float2bfloat16(ax);
        st.b = __float2bfloat16(ay);
        st.c = __float2bfloat16(az);
        st.d = __float2bfloat16(aw);
        *(bf4*)(ea_t + (size_t)(j - e0) * DIN + fq * 4) = st;
    }
}

// ---------------------------------------------------------------------------
// CSR aggregate (gather-reduce only): node chunk [v0,v1).
//   agg[v][f] = sum_j relu(h[src_j][f] + ea_t[j - e0][f])
// Per edge per thread: one 4B h load + one 2B ea_t load (+uniform src).
// ---------------------------------------------------------------------------
template<int DIN>
__global__ __launch_bounds__(256) void gine_agg_kernel(
    const float* __restrict__ h, const __hip_bfloat16* __restrict__ ea_t,
    const int* __restrict__ perm_src,
    const int* __restrict__ rowstart, const int* __restrict__ rowend,
    int v0, int v1, float* __restrict__ agg)
{
    const int f = threadIdx.x & (DIN - 1);
    const int g = threadIdx.x / DIN;
    constexpr int GPB = 256 / DIN;
    const int v = v0 + blockIdx.x * GPB + g;
    if (v >= v1) return;

    const int e0 = rowstart[v0];
    const int s0 = rowstart[v];
    const int s1 = rowend[v];

    float acc = 0.f;
    int j = s0;
    for (; j + 4 <= s1; j += 4) {
        const int sn0 = perm_src[j + 0];
        const int sn1 = perm_src[j + 1];
        const int sn2 = perm_src[j + 2];
        const int sn3 = perm_src[j + 3];
        const float hv0 = h[(size_t)sn0 * DIN + f];
        const float hv1 = h[(size_t)sn1 * DIN + f];
        const float hv2 = h[(size_t)sn2 * DIN + f];
        const float hv3 = h[(size_t)sn3 * DIN + f];
        const float e0v = __bfloat162float(ea_t[(size_t)(j + 0 - e0) * DIN + f]);
        const float e1v = __bfloat162float(ea_t[(size_t)(j + 1 - e0) * DIN + f]);
        const float e2v = __bfloat162float(ea_t[(size_t)(j + 2 - e0) * DIN + f]);
        const float e3v = __bfloat162float(ea_t[(size_t)(j + 3 - e0) * DIN + f]);
        acc += fmaxf(hv0 + e0v, 0.f) + fmaxf(hv1 + e1v, 0.f)
             + fmaxf(hv2 + e2v, 0.f) + fmaxf(hv3 + e3v, 0.f);
    }
    for (; j < s1; ++j) {
        const int sn = perm_src[j];
        const float hv = h[(size_t)sn * DIN + f];
        const float ev = __bfloat162float(ea_t[(size_t)(j - e0) * DIN + f]);
        acc += fmaxf(hv + ev, 0.f);
    }
    agg[(size_t)v * DIN + f] = acc;
}

// ---------------------------------------------------------------------------
// Node kernel: register-tiled 4x4 (unchanged from round 3).
// ---------------------------------------------------------------------------
#define OUTER4(acc, xv, wv)                                              \
    do {                                                                 \
        acc[0][0] = fmaf(xv.x, wv.x, acc[0][0]);                         \
        acc[0][1] = fmaf(xv.x, wv.y, acc[0][1]);                         \
        acc[0][2] = fmaf(xv.x, wv.z, acc[0][2]);                         \
        acc[0][3] = fmaf(xv.x, wv.w, acc[0][3]);                         \
        acc[1][0] = fmaf(xv.y, wv.x, acc[1][0]);                         \
        acc[1][1] = fmaf(xv.y, wv.y, acc[1][1]);                         \
        acc[1][2] = fmaf(xv.y, wv.z, acc[1][2]);                         \
        acc[1][3] = fmaf(xv.y, wv.w, acc[1][3]);                         \
        acc[2][0] = fmaf(xv.z, wv.x, acc[2][0]);                         \
        acc[2][1] = fmaf(xv.z, wv.y, acc[2][1]);                         \
        acc[2][2] = fmaf(xv.z, wv.z, acc[2][2]);                         \
        acc[2][3] = fmaf(xv.z, wv.w, acc[2][3]);                         \
        acc[3][0] = fmaf(xv.w, wv.x, acc[3][0]);                         \
        acc[3][1] = fmaf(xv.w, wv.y, acc[3][1]);                         \
        acc[3][2] = fmaf(xv.w, wv.z, acc[3][2]);                         \
        acc[3][3] = fmaf(xv.w, wv.w, acc[3][3]);                         \
    } while (0)

template<int DIN>
__global__ __launch_bounds__(256) void node_kernel(
    const float* __restrict__ h, const float* __restrict__ agg,
    const float* __restrict__ w1, const float* __restrict__ b1,
    const float* __restrict__ gm, const float* __restrict__ bt,
    const float* __restrict__ w2, const float* __restrict__ b2,
    float* __restrict__ hout, int n_nodes)
{
    __shared__ float s_x[DIN][36];
    __shared__ float s_t[HID_C][36];

    const int tid = threadIdx.x;
    const int fg = tid & 31;
    const int ng = tid >> 5;
    const int base = blockIdx.x * 32;

    constexpr int KQ = DIN / 4;
    for (int idx = tid; idx < 32 * KQ; idx += 256) {
        const int ni = idx / KQ;
        const int k4 = (idx - ni * KQ) * 4;
        const int node = base + ni;
        const float4 hv = *(const float4*)(h   + (size_t)node * DIN + k4);
        const float4 av = *(const float4*)(agg + (size_t)node * DIN + k4);
        s_x[k4 + 0][ni] = hv.x + av.x;
        s_x[k4 + 1][ni] = hv.y + av.y;
        s_x[k4 + 2][ni] = hv.z + av.z;
        s_x[k4 + 3][ni] = hv.w + av.w;
    }
    __syncthreads();

    {
        const float4 b1v = *(const float4*)(b1 + fg * 4);
        float acc[4][4];
#pragma unroll
        for (int ni = 0; ni < 4; ++ni) {
            acc[ni][0] = b1v.x; acc[ni][1] = b1v.y;
            acc[ni][2] = b1v.z; acc[ni][3] = b1v.w;
        }
#pragma unroll 4
        for (int k = 0; k < DIN; ++k) {
            const float4 wv = *(const float4*)(w1 + (size_t)k * HID_C + fg * 4);
            const float4 xv = *(const float4*)(&s_x[k][ng * 4]);
            OUTER4(acc, xv, wv);
        }
        const float4 gv  = *(const float4*)(gm + fg * 4);
        const float4 btv = *(const float4*)(bt + fg * 4);
        const float ga[4]  = {gv.x, gv.y, gv.z, gv.w};
        const float bta[4] = {btv.x, btv.y, btv.z, btv.w};
#pragma unroll
        for (int fi = 0; fi < 4; ++fi) {
            float4 tv;
            tv.x = fmaxf(fmaf(acc[0][fi] * BN_SCALE_C, ga[fi], bta[fi]), 0.f);
            tv.y = fmaxf(fmaf(acc[1][fi] * BN_SCALE_C, ga[fi], bta[fi]), 0.f);
            tv.z = fmaxf(fmaf(acc[2][fi] * BN_SCALE_C, ga[fi], bta[fi]), 0.f);
            tv.w = fmaxf(fmaf(acc[3][fi] * BN_SCALE_C, ga[fi], bta[fi]), 0.f);
            *(float4*)(&s_t[fg * 4 + fi][ng * 4]) = tv;
        }
    }
    __syncthreads();

    {
        const float4 b2v = *(const float4*)(b2 + fg * 4);
        float acc[4][4];
#pragma unroll
        for (int ni = 0; ni < 4; ++ni) {
            acc[ni][0] = b2v.x; acc[ni][1] = b2v.y;
            acc[ni][2] = b2v.z; acc[ni][3] = b2v.w;
        }
#pragma unroll 4
        for (int k = 0; k < HID_C; ++k) {
            const float4 wv = *(const float4*)(w2 + (size_t)k * HID_C + fg * 4);
            const float4 xv = *(const float4*)(&s_t[k][ng * 4]);
            OUTER4(acc, xv, wv);
        }
#pragma unroll
        for (int ni = 0; ni < 4; ++ni) {
            const int node = base + ng * 4 + ni;
            float4 ov;
            ov.x = fmaxf(acc[ni][0], 0.f);
            ov.y = fmaxf(acc[ni][1], 0.f);
            ov.z = fmaxf(acc[ni][2], 0.f);
            ov.w = fmaxf(acc[ni][3], 0.f);
            *(float4*)(hout + (size_t)node * HID_C + fg * 4) = ov;
        }
    }
}

// ---------------------------------------------------------------------------
// Pool + output MLP (unchanged).
// ---------------------------------------------------------------------------
__global__ __launch_bounds__(256) void pool_kernel(
    const float* __restrict__ hfin, const int* __restrict__ batch,
    const float* __restrict__ w1, const float* __restrict__ b1,
    const float* __restrict__ w2, const float* __restrict__ b2,
    float* __restrict__ out, int n_nodes)
{
    const int gid = blockIdx.x;

    int lo = 0, hi = n_nodes;
    while (lo < hi) { int mid = (lo + hi) >> 1; if (batch[mid] < gid) lo = mid + 1; else hi = mid; }
    const int start = lo;
    hi = n_nodes;
    while (lo < hi) { int mid = (lo + hi) >> 1; if (batch[mid] < gid + 1) lo = mid + 1; else hi = mid; }
    const int end = lo;

    const int f = threadIdx.x & (HID_C - 1);
    const int half = threadIdx.x >> 7;

    float sum = 0.f;
    for (int n = start + half; n < end; n += 2)
        sum += hfin[(size_t)n * HID_C + f];

    __shared__ float s_sum[2][HID_C];
    __shared__ float s_p[HID_C];
    __shared__ float s_t[HID_C];
    s_sum[half][f] = sum;
    __syncthreads();

    if (threadIdx.x < HID_C) {
        const float cnt = (float)(end - start);
        s_p[f] = (s_sum[0][f] + s_sum[1][f]) / fmaxf(cnt, 1.f);
    }
    __syncthreads();

    if (threadIdx.x < HID_C) {
        float acc = b1[f];
        for (int k = 0; k < HID_C; ++k) acc = fmaf(s_p[k], w1[k * HID_C + f], acc);
        s_t[f] = fmaxf(acc, 0.f);
    }
    __syncthreads();

    if (threadIdx.x < HID_C) {
        float acc = b2[f];
        for (int k = 0; k < HID_C; ++k) acc = fmaf(s_t[k], w2[k * HID_C + f], acc);
        out[(size_t)gid * HID_C + f] = acc;
    }
}

// ---------------------------------------------------------------------------
extern "C" void kernel_launch(void* const* d_in, const int* in_sizes, int n_in,
                              void* d_out, int out_size, void* d_ws, size_t ws_size,
                              hipStream_t stream)
{
    const float* x         = (const float*)d_in[0];
    const float* edge_attr = (const float*)d_in[1];
    const int*   edge_index= (const int*)  d_in[2];
    const int*   batch     = (const int*)  d_in[3];
    const int*   src = edge_index;
    const int*   dst = edge_index + N_EDGES_C;

    const float* el_w[3] = {(const float*)d_in[4],  (const float*)d_in[12], (const float*)d_in[20]};
    const float* el_b[3] = {(const float*)d_in[5],  (const float*)d_in[13], (const float*)d_in[21]};
    const float* c_w1[3] = {(const float*)d_in[6],  (const float*)d_in[14], (const float*)d_in[22]};
    const float* c_b1[3] = {(const float*)d_in[7],  (const float*)d_in[15], (const float*)d_in[23]};
    const float* c_g [3] = {(const float*)d_in[8],  (const float*)d_in[16], (const float*)d_in[24]};
    const float* c_bt[3] = {(const float*)d_in[9],  (const float*)d_in[17], (const float*)d_in[25]};
    const float* c_w2[3] = {(const float*)d_in[10], (const float*)d_in[18], (const float*)d_in[26]};
    const float* c_b2[3] = {(const float*)d_in[11], (const float*)d_in[19], (const float*)d_in[27]};
    const float* o_w1 = (const float*)d_in[28];
    const float* o_b1 = (const float*)d_in[29];
    const float* o_w2 = (const float*)d_in[30];
    const float* o_b2 = (const float*)d_in[31];

    // ---- workspace layout (~194 MB; round 3 proved ws >= 219 MB) ----
    char* wsp = (char*)d_ws;
    size_t used = 0;
    auto alloc = [&](size_t bytes) { char* p = wsp + used; used += (bytes + 255) & ~(size_t)255; return p; };
    float* h        = (float*)alloc((size_t)N_NODES_C * HID_C * 4);
    float* agg      = (float*)alloc((size_t)N_NODES_C * HID_C * 4);
    int*   counts   = (int*)alloc((size_t)N_NODES_C * 4);
    int*   incl     = (int*)alloc((size_t)N_NODES_C * 4);
    int*   rowstart = (int*)alloc((size_t)N_NODES_C * 4);
    int*   cursor   = (int*)alloc((size_t)N_NODES_C * 4);
    int*   blocksums= (int*)alloc(128 * 4);
    int*   blockoffs= (int*)alloc(128 * 4);
    int*   perm_src = (int*)alloc((size_t)N_EDGES_C * 4);
    int*   perm_eid = (int*)alloc((size_t)N_EDGES_C * 4);
    __hip_bfloat16* ea_t = (__hip_bfloat16*)alloc((size_t)CAP_EDGES * HID_C * 2);
    (void)ws_size;

    // ---- CSR build (once; reused by all 3 layers) ----
    hipMemsetAsync(counts, 0, (size_t)N_NODES_C * 4, stream);
    hist_kernel<<<(N_EDGES_C + 255) / 256, 256, 0, stream>>>(dst, counts, N_EDGES_C);
    scan1_kernel<<<SCAN_NB, SCAN_B, 0, stream>>>(counts, incl, blocksums, N_NODES_C);
    scan2_kernel<<<1, 64, 0, stream>>>(blocksums, blockoffs, SCAN_NB);
    scan3_kernel<<<SCAN_NB, SCAN_B, 0, stream>>>(incl, blockoffs, N_NODES_C);
    initrows_kernel<<<(N_NODES_C + 255) / 256, 256, 0, stream>>>(incl, counts, rowstart,
                                                                 cursor, N_NODES_C);
    scatter_kernel<<<(N_EDGES_C + 255) / 256, 256, 0, stream>>>(src, dst, cursor,
                                                                perm_src, perm_eid, N_EDGES_C);

    // ---- 3 GINE layers, edge phase chunked 8x by node range ----
    for (int l = 0; l < 3; ++l) {
        const float* hin = (l == 0) ? x : h;
        for (int c = 0; c < N_CHUNKS; ++c) {
            const int v0 = c * CHUNK_NODES;
            const int v1 = v0 + CHUNK_NODES;
            if (l == 0) {
                edge_mlp_kernel<64><<<CAP_EDGES / 16, 256, 0, stream>>>(
                    edge_attr, perm_eid, rowstart, v0, v1, el_w[0], el_b[0],
                    ea_t, N_EDGES_C);
                gine_agg_kernel<64><<<CHUNK_NODES / 4, 256, 0, stream>>>(
                    hin, ea_t, perm_src, rowstart, incl, v0, v1, agg);
            } else {
                edge_mlp_kernel<128><<<CAP_EDGES / 8, 256, 0, stream>>>(
                    edge_attr, perm_eid, rowstart, v0, v1, el_w[l], el_b[l],
                    ea_t, N_EDGES_C);
                gine_agg_kernel<128><<<CHUNK_NODES / 2, 256, 0, stream>>>(
                    hin, ea_t, perm_src, rowstart, incl, v0, v1, agg);
            }
        }
        if (l == 0)
            node_kernel<64><<<N_NODES_C / 32, 256, 0, stream>>>(
                hin, agg, c_w1[0], c_b1[0], c_g[0], c_bt[0], c_w2[0], c_b2[0],
                h, N_NODES_C);
        else
            node_kernel<128><<<N_NODES_C / 32, 256, 0, stream>>>(
                hin, agg, c_w1[l], c_b1[l], c_g[l], c_bt[l], c_w2[l], c_b2[l],
                h, N_NODES_C);
    }

    // ---- pool + output MLP ----
    pool_kernel<<<N_GRAPHS_C, 256, 0, stream>>>(h, batch, o_w1, o_b1, o_w2, o_b2,
                                                (float*)d_out, N_NODES_C);
}

// Round 5
// 1286.810 us; speedup vs baseline: 2.1245x; 2.1245x over previous
//
#include <hip/hip_runtime.h>
#include <cstdint>
#include <cstddef>

#define N_NODES_C  100000
#define N_EDGES_C  1600000
#define N_GRAPHS_C 256
#define HID_C      128
// 1/sqrt(1+1e-5)
#define BN_SCALE_C 0.9999950000374997f

#define SCAN_B 1024
#define SCAN_NB ((N_NODES_C + SCAN_B - 1) / SCAN_B)   // 98

// ---------------------------------------------------------------------------
// CSR build: histogram of dst, inclusive scan, scatter edge ids.
// ---------------------------------------------------------------------------
__global__ __launch_bounds__(256) void hist_kernel(
    const int* __restrict__ dst, int* __restrict__ counts, int n_edges)
{
    int e = blockIdx.x * 256 + threadIdx.x;
    if (e < n_edges) atomicAdd(&counts[dst[e]], 1);
}

__global__ __launch_bounds__(SCAN_B) void scan1_kernel(
    const int* __restrict__ counts, int* __restrict__ incl,
    int* __restrict__ blocksums, int n)
{
    __shared__ int sdata[SCAN_B];
    const int lid = threadIdx.x;
    const int i = blockIdx.x * SCAN_B + lid;
    sdata[lid] = (i < n) ? counts[i] : 0;
    __syncthreads();
#pragma unroll
    for (int off = 1; off < SCAN_B; off <<= 1) {
        int t = (lid >= off) ? sdata[lid - off] : 0;
        __syncthreads();
        sdata[lid] += t;
        __syncthreads();
    }
    if (i < n) incl[i] = sdata[lid];
    if (lid == SCAN_B - 1) blocksums[blockIdx.x] = sdata[lid];
}

__global__ void scan2_kernel(const int* __restrict__ blocksums,
                             int* __restrict__ blockoffs, int nb)
{
    if (threadIdx.x == 0 && blockIdx.x == 0) {
        int off = 0;
        for (int b = 0; b < nb; ++b) { blockoffs[b] = off; off += blocksums[b]; }
    }
}

__global__ __launch_bounds__(SCAN_B) void scan3_kernel(
    int* __restrict__ incl, const int* __restrict__ blockoffs, int n)
{
    const int i = blockIdx.x * SCAN_B + threadIdx.x;
    if (i < n) incl[i] += blockoffs[blockIdx.x];
}

__global__ __launch_bounds__(256) void initrows_kernel(
    const int* __restrict__ incl, const int* __restrict__ counts,
    int* __restrict__ rowstart, int* __restrict__ cursor, int n)
{
    const int i = blockIdx.x * 256 + threadIdx.x;
    if (i < n) {
        const int rs = incl[i] - counts[i];
        rowstart[i] = rs;
        cursor[i]   = rs;
    }
}

__global__ __launch_bounds__(256) void scatter_kernel(
    const int* __restrict__ src, const int* __restrict__ dst,
    int* __restrict__ cursor, int* __restrict__ perm_src,
    int* __restrict__ perm_eid, int n_edges)
{
    const int e = blockIdx.x * 256 + threadIdx.x;
    if (e < n_edges) {
        const int pos = atomicAdd(&cursor[dst[e]], 1);
        perm_src[pos] = src[e];
        perm_eid[pos] = e;
    }
}

// Gather edge_attr rows into CSR order: coalesced writes, random 64B reads.
__global__ __launch_bounds__(256) void permute_ea_kernel(
    const float* __restrict__ edge_attr, const int* __restrict__ perm_eid,
    float* __restrict__ ea_perm, int n_edges)
{
    const int t = blockIdx.x * 256 + threadIdx.x;
    const int j = t >> 2;
    const int q = t & 3;
    if (j < n_edges) {
        const int eid = perm_eid[j];
        ((float4*)(ea_perm + (size_t)j * 16))[q] =
            ((const float4*)(edge_attr + (size_t)eid * 16))[q];
    }
}

// ---------------------------------------------------------------------------
// CSR aggregate, quad-per-lane: each lane owns 4 consecutive features.
// ew quad-columns (16 x float4 = 64 VGPR) in registers; h gathers are
// dwordx4; one wave serves 2 (DIN=128) / 4 (DIN=64) nodes. Unroll x2 keeps
// 2 gather chains in flight. No extra global traffic vs inline compute.
// ---------------------------------------------------------------------------
__device__ __forceinline__ float4 eamlp4(const float4* __restrict__ p,
                                         const float4* ewr, float4 m)
{
    const float4 q0 = p[0], q1 = p[1], q2 = p[2], q3 = p[3];
    const float a[16] = {q0.x, q0.y, q0.z, q0.w, q1.x, q1.y, q1.z, q1.w,
                         q2.x, q2.y, q2.z, q2.w, q3.x, q3.y, q3.z, q3.w};
#pragma unroll
    for (int k = 0; k < 16; ++k) {
        m.x = fmaf(a[k], ewr[k].x, m.x);
        m.y = fmaf(a[k], ewr[k].y, m.y);
        m.z = fmaf(a[k], ewr[k].z, m.z);
        m.w = fmaf(a[k], ewr[k].w, m.w);
    }
    return m;
}

template<int DIN, bool PERM>
__global__ __launch_bounds__(256) void gine_agg_kernel(
    const float* __restrict__ h, const float* __restrict__ edge_attr,
    const float* __restrict__ ea_perm,
    const int* __restrict__ perm_src, const int* __restrict__ perm_eid,
    const int* __restrict__ rowstart, const int* __restrict__ rowend,
    const float* __restrict__ ew, const float* __restrict__ eb,
    float* __restrict__ agg, int n_nodes)
{
    constexpr int NQ    = DIN / 4;     // feature quads per node: 32 / 16
    constexpr int SLOTS = 256 / NQ;    // nodes per block: 8 / 16
    const int fq   = threadIdx.x & (NQ - 1);
    const int slot = threadIdx.x / NQ;
    const int v = blockIdx.x * SLOTS + slot;
    if (v >= n_nodes) return;

    float4 ewr[16];
#pragma unroll
    for (int k = 0; k < 16; ++k)
        ewr[k] = *(const float4*)(ew + (size_t)k * DIN + fq * 4);
    const float4 ebv = *(const float4*)(eb + fq * 4);

    const int s0 = rowstart[v];
    const int s1 = rowend[v];

    float4 acc = {0.f, 0.f, 0.f, 0.f};
    int j = s0;
    for (; j + 2 <= s1; j += 2) {
        const int sn0 = perm_src[j + 0];
        const int sn1 = perm_src[j + 1];
        const float4 hv0 = *(const float4*)(h + (size_t)sn0 * DIN + fq * 4);
        const float4 hv1 = *(const float4*)(h + (size_t)sn1 * DIN + fq * 4);
        const float4 *p0, *p1;
        if (PERM) {
            p0 = (const float4*)(ea_perm + (size_t)(j + 0) * 16);
            p1 = (const float4*)(ea_perm + (size_t)(j + 1) * 16);
        } else {
            p0 = (const float4*)(edge_attr + (size_t)perm_eid[j + 0] * 16);
            p1 = (const float4*)(edge_attr + (size_t)perm_eid[j + 1] * 16);
        }
        const float4 m0 = eamlp4(p0, ewr, ebv);
        const float4 m1 = eamlp4(p1, ewr, ebv);
        acc.x += fmaxf(m0.x + hv0.x, 0.f) + fmaxf(m1.x + hv1.x, 0.f);
        acc.y += fmaxf(m0.y + hv0.y, 0.f) + fmaxf(m1.y + hv1.y, 0.f);
        acc.z += fmaxf(m0.z + hv0.z, 0.f) + fmaxf(m1.z + hv1.z, 0.f);
        acc.w += fmaxf(m0.w + hv0.w, 0.f) + fmaxf(m1.w + hv1.w, 0.f);
    }
    if (j < s1) {
        const int sn = perm_src[j];
        const float4 hv = *(const float4*)(h + (size_t)sn * DIN + fq * 4);
        const float4* p = PERM ? (const float4*)(ea_perm + (size_t)j * 16)
                               : (const float4*)(edge_attr + (size_t)perm_eid[j] * 16);
        const float4 m = eamlp4(p, ewr, ebv);
        acc.x += fmaxf(m.x + hv.x, 0.f);
        acc.y += fmaxf(m.y + hv.y, 0.f);
        acc.z += fmaxf(m.z + hv.z, 0.f);
        acc.w += fmaxf(m.w + hv.w, 0.f);
    }
    *(float4*)(agg + (size_t)v * DIN + fq * 4) = acc;
}

// ---------------------------------------------------------------------------
// Node kernel v3: natural-orientation LDS tiles (conflict-free).
//   s_x[node][k] stride DIN+4, s_t[node][f] stride 132.
// k-loop steps by 4: per group, 4 b128 LDS broadcasts (one per node) +
// 4 float4 global w rows + 64 FMA. All LDS writes are stride-1 b128.
// ---------------------------------------------------------------------------
#define OUT4(acc, a0, a1, a2, a3, wv)                                     \
    do {                                                                  \
        acc[0][0] = fmaf(a0, wv.x, acc[0][0]);                            \
        acc[0][1] = fmaf(a0, wv.y, acc[0][1]);                            \
        acc[0][2] = fmaf(a0, wv.z, acc[0][2]);                            \
        acc[0][3] = fmaf(a0, wv.w, acc[0][3]);                            \
        acc[1][0] = fmaf(a1, wv.x, acc[1][0]);                            \
        acc[1][1] = fmaf(a1, wv.y, acc[1][1]);                            \
        acc[1][2] = fmaf(a1, wv.z, acc[1][2]);                            \
        acc[1][3] = fmaf(a1, wv.w, acc[1][3]);                            \
        acc[2][0] = fmaf(a2, wv.x, acc[2][0]);                            \
        acc[2][1] = fmaf(a2, wv.y, acc[2][1]);                            \
        acc[2][2] = fmaf(a2, wv.z, acc[2][2]);                            \
        acc[2][3] = fmaf(a2, wv.w, acc[2][3]);                            \
        acc[3][0] = fmaf(a3, wv.x, acc[3][0]);                            \
        acc[3][1] = fmaf(a3, wv.y, acc[3][1]);                            \
        acc[3][2] = fmaf(a3, wv.z, acc[3][2]);                            \
        acc[3][3] = fmaf(a3, wv.w, acc[3][3]);                            \
    } while (0)

template<int DIN>
__global__ __launch_bounds__(256) void node_kernel(
    const float* __restrict__ h, const float* __restrict__ agg,
    const float* __restrict__ w1, const float* __restrict__ b1,
    const float* __restrict__ gm, const float* __restrict__ bt,
    const float* __restrict__ w2, const float* __restrict__ b2,
    float* __restrict__ hout, int n_nodes)
{
    constexpr int SX = DIN + 4;
    constexpr int ST = HID_C + 4;
    __shared__ float s_x[32][SX];
    __shared__ float s_t[32][ST];

    const int tid = threadIdx.x;
    const int fg = tid & 31;          // feature quad -> f = fg*4
    const int ng = tid >> 5;          // node quad    -> nodes ng*4 .. ng*4+3
    const int base = blockIdx.x * 32;

    constexpr int KQ = DIN / 4;
    for (int idx = tid; idx < 32 * KQ; idx += 256) {
        const int ni = idx / KQ;
        const int k4 = (idx - ni * KQ) * 4;
        const int node = base + ni;
        const float4 hv = *(const float4*)(h   + (size_t)node * DIN + k4);
        const float4 av = *(const float4*)(agg + (size_t)node * DIN + k4);
        float4 s; s.x = hv.x + av.x; s.y = hv.y + av.y;
        s.z = hv.z + av.z; s.w = hv.w + av.w;
        *(float4*)(&s_x[ni][k4]) = s;
    }
    __syncthreads();

    // ---- mm1 + BN + relu ----
    {
        const float4 b1v = *(const float4*)(b1 + fg * 4);
        float acc[4][4];
#pragma unroll
        for (int ni = 0; ni < 4; ++ni) {
            acc[ni][0] = b1v.x; acc[ni][1] = b1v.y;
            acc[ni][2] = b1v.z; acc[ni][3] = b1v.w;
        }
        for (int k = 0; k < DIN; k += 4) {
            const float4 x0 = *(const float4*)(&s_x[ng * 4 + 0][k]);
            const float4 x1 = *(const float4*)(&s_x[ng * 4 + 1][k]);
            const float4 x2 = *(const float4*)(&s_x[ng * 4 + 2][k]);
            const float4 x3 = *(const float4*)(&s_x[ng * 4 + 3][k]);
            const float4 wa = *(const float4*)(w1 + (size_t)(k + 0) * HID_C + fg * 4);
            const float4 wb = *(const float4*)(w1 + (size_t)(k + 1) * HID_C + fg * 4);
            const float4 wc = *(const float4*)(w1 + (size_t)(k + 2) * HID_C + fg * 4);
            const float4 wd = *(const float4*)(w1 + (size_t)(k + 3) * HID_C + fg * 4);
            OUT4(acc, x0.x, x1.x, x2.x, x3.x, wa);
            OUT4(acc, x0.y, x1.y, x2.y, x3.y, wb);
            OUT4(acc, x0.z, x1.z, x2.z, x3.z, wc);
            OUT4(acc, x0.w, x1.w, x2.w, x3.w, wd);
        }
        const float4 gv  = *(const float4*)(gm + fg * 4);
        const float4 btv = *(const float4*)(bt + fg * 4);
#pragma unroll
        for (int ni = 0; ni < 4; ++ni) {
            float4 tv;
            tv.x = fmaxf(fmaf(acc[ni][0] * BN_SCALE_C, gv.x, btv.x), 0.f);
            tv.y = fmaxf(fmaf(acc[ni][1] * BN_SCALE_C, gv.y, btv.y), 0.f);
            tv.z = fmaxf(fmaf(acc[ni][2] * BN_SCALE_C, gv.z, btv.z), 0.f);
            tv.w = fmaxf(fmaf(acc[ni][3] * BN_SCALE_C, gv.w, btv.w), 0.f);
            *(float4*)(&s_t[ng * 4 + ni][fg * 4]) = tv;
        }
    }
    __syncthreads();

    // ---- mm2 + relu ----
    {
        const float4 b2v = *(const float4*)(b2 + fg * 4);
        float acc[4][4];
#pragma unroll
        for (int ni = 0; ni < 4; ++ni) {
            acc[ni][0] = b2v.x; acc[ni][1] = b2v.y;
            acc[ni][2] = b2v.z; acc[ni][3] = b2v.w;
        }
        for (int k = 0; k < HID_C; k += 4) {
            const float4 x0 = *(const float4*)(&s_t[ng * 4 + 0][k]);
            const float4 x1 = *(const float4*)(&s_t[ng * 4 + 1][k]);
            const float4 x2 = *(const float4*)(&s_t[ng * 4 + 2][k]);
            const float4 x3 = *(const float4*)(&s_t[ng * 4 + 3][k]);
            const float4 wa = *(const float4*)(w2 + (size_t)(k + 0) * HID_C + fg * 4);
            const float4 wb = *(const float4*)(w2 + (size_t)(k + 1) * HID_C + fg * 4);
            const float4 wc = *(const float4*)(w2 + (size_t)(k + 2) * HID_C + fg * 4);
            const float4 wd = *(const float4*)(w2 + (size_t)(k + 3) * HID_C + fg * 4);
            OUT4(acc, x0.x, x1.x, x2.x, x3.x, wa);
            OUT4(acc, x0.y, x1.y, x2.y, x3.y, wb);
            OUT4(acc, x0.z, x1.z, x2.z, x3.z, wc);
            OUT4(acc, x0.w, x1.w, x2.w, x3.w, wd);
        }
#pragma unroll
        for (int ni = 0; ni < 4; ++ni) {
            const int node = base + ng * 4 + ni;
            float4 ov;
            ov.x = fmaxf(acc[ni][0], 0.f);
            ov.y = fmaxf(acc[ni][1], 0.f);
            ov.z = fmaxf(acc[ni][2], 0.f);
            ov.w = fmaxf(acc[ni][3], 0.f);
            *(float4*)(hout + (size_t)node * HID_C + fg * 4) = ov;
        }
    }
}

// ---------------------------------------------------------------------------
// Pool + output MLP (unchanged).
// ---------------------------------------------------------------------------
__global__ __launch_bounds__(256) void pool_kernel(
    const float* __restrict__ hfin, const int* __restrict__ batch,
    const float* __restrict__ w1, const float* __restrict__ b1,
    const float* __restrict__ w2, const float* __restrict__ b2,
    float* __restrict__ out, int n_nodes)
{
    const int gid = blockIdx.x;

    int lo = 0, hi = n_nodes;
    while (lo < hi) { int mid = (lo + hi) >> 1; if (batch[mid] < gid) lo = mid + 1; else hi = mid; }
    const int start = lo;
    hi = n_nodes;
    while (lo < hi) { int mid = (lo + hi) >> 1; if (batch[mid] < gid + 1) lo = mid + 1; else hi = mid; }
    const int end = lo;

    const int f = threadIdx.x & (HID_C - 1);
    const int half = threadIdx.x >> 7;

    float sum = 0.f;
    for (int n = start + half; n < end; n += 2)
        sum += hfin[(size_t)n * HID_C + f];

    __shared__ float s_sum[2][HID_C];
    __shared__ float s_p[HID_C];
    __shared__ float s_t[HID_C];
    s_sum[half][f] = sum;
    __syncthreads();

    if (threadIdx.x < HID_C) {
        const float cnt = (float)(end - start);
        s_p[f] = (s_sum[0][f] + s_sum[1][f]) / fmaxf(cnt, 1.f);
    }
    __syncthreads();

    if (threadIdx.x < HID_C) {
        float acc = b1[f];
        for (int k = 0; k < HID_C; ++k) acc = fmaf(s_p[k], w1[k * HID_C + f], acc);
        s_t[f] = fmaxf(acc, 0.f);
    }
    __syncthreads();

    if (threadIdx.x < HID_C) {
        float acc = b2[f];
        for (int k = 0; k < HID_C; ++k) acc = fmaf(s_t[k], w2[k * HID_C + f], acc);
        out[(size_t)gid * HID_C + f] = acc;
    }
}

// ---------------------------------------------------------------------------
extern "C" void kernel_launch(void* const* d_in, const int* in_sizes, int n_in,
                              void* d_out, int out_size, void* d_ws, size_t ws_size,
                              hipStream_t stream)
{
    const float* x         = (const float*)d_in[0];
    const float* edge_attr = (const float*)d_in[1];
    const int*   edge_index= (const int*)  d_in[2];
    const int*   batch     = (const int*)  d_in[3];
    const int*   src = edge_index;
    const int*   dst = edge_index + N_EDGES_C;

    const float* el_w[3] = {(const float*)d_in[4],  (const float*)d_in[12], (const float*)d_in[20]};
    const float* el_b[3] = {(const float*)d_in[5],  (const float*)d_in[13], (const float*)d_in[21]};
    const float* c_w1[3] = {(const float*)d_in[6],  (const float*)d_in[14], (const float*)d_in[22]};
    const float* c_b1[3] = {(const float*)d_in[7],  (const float*)d_in[15], (const float*)d_in[23]};
    const float* c_g [3] = {(const float*)d_in[8],  (const float*)d_in[16], (const float*)d_in[24]};
    const float* c_bt[3] = {(const float*)d_in[9],  (const float*)d_in[17], (const float*)d_in[25]};
    const float* c_w2[3] = {(const float*)d_in[10], (const float*)d_in[18], (const float*)d_in[26]};
    const float* c_b2[3] = {(const float*)d_in[11], (const float*)d_in[19], (const float*)d_in[27]};
    const float* o_w1 = (const float*)d_in[28];
    const float* o_b1 = (const float*)d_in[29];
    const float* o_w2 = (const float*)d_in[30];
    const float* o_b2 = (const float*)d_in[31];

    // ---- workspace layout ----
    char* wsp = (char*)d_ws;
    size_t used = 0;
    auto alloc = [&](size_t bytes) { char* p = wsp + used; used += (bytes + 255) & ~(size_t)255; return p; };
    float* h        = (float*)alloc((size_t)N_NODES_C * HID_C * 4);
    float* agg      = (float*)alloc((size_t)N_NODES_C * HID_C * 4);
    int*   counts   = (int*)alloc((size_t)N_NODES_C * 4);
    int*   incl     = (int*)alloc((size_t)N_NODES_C * 4);
    int*   rowstart = (int*)alloc((size_t)N_NODES_C * 4);
    int*   cursor   = (int*)alloc((size_t)N_NODES_C * 4);
    int*   blocksums= (int*)alloc(128 * 4);
    int*   blockoffs= (int*)alloc(128 * 4);
    int*   perm_src = (int*)alloc((size_t)N_EDGES_C * 4);
    int*   perm_eid = (int*)alloc((size_t)N_EDGES_C * 4);
    float* ea_perm  = (float*)alloc((size_t)N_EDGES_C * 16 * 4);
    const bool use_perm = (used <= ws_size);

    // ---- CSR build (once; reused by all 3 layers) ----
    hipMemsetAsync(counts, 0, (size_t)N_NODES_C * 4, stream);
    hist_kernel<<<(N_EDGES_C + 255) / 256, 256, 0, stream>>>(dst, counts, N_EDGES_C);
    scan1_kernel<<<SCAN_NB, SCAN_B, 0, stream>>>(counts, incl, blocksums, N_NODES_C);
    scan2_kernel<<<1, 64, 0, stream>>>(blocksums, blockoffs, SCAN_NB);
    scan3_kernel<<<SCAN_NB, SCAN_B, 0, stream>>>(incl, blockoffs, N_NODES_C);
    initrows_kernel<<<(N_NODES_C + 255) / 256, 256, 0, stream>>>(incl, counts, rowstart,
                                                                 cursor, N_NODES_C);
    scatter_kernel<<<(N_EDGES_C + 255) / 256, 256, 0, stream>>>(src, dst, cursor,
                                                                perm_src, perm_eid, N_EDGES_C);
    if (use_perm)
        permute_ea_kernel<<<(N_EDGES_C * 4 + 255) / 256, 256, 0, stream>>>(
            edge_attr, perm_eid, ea_perm, N_EDGES_C);

    // ---- 3 GINE layers ----
    for (int l = 0; l < 3; ++l) {
        const float* hin = (l == 0) ? x : h;
        if (l == 0) {
            if (use_perm)
                gine_agg_kernel<64, true><<<(N_NODES_C + 15) / 16, 256, 0, stream>>>(
                    hin, edge_attr, ea_perm, perm_src, perm_eid, rowstart, incl,
                    el_w[0], el_b[0], agg, N_NODES_C);
            else
                gine_agg_kernel<64, false><<<(N_NODES_C + 15) / 16, 256, 0, stream>>>(
                    hin, edge_attr, ea_perm, perm_src, perm_eid, rowstart, incl,
                    el_w[0], el_b[0], agg, N_NODES_C);
            node_kernel<64><<<N_NODES_C / 32, 256, 0, stream>>>(
                hin, agg, c_w1[0], c_b1[0], c_g[0], c_bt[0], c_w2[0], c_b2[0],
                h, N_NODES_C);
        } else {
            if (use_perm)
                gine_agg_kernel<128, true><<<(N_NODES_C + 7) / 8, 256, 0, stream>>>(
                    hin, edge_attr, ea_perm, perm_src, perm_eid, rowstart, incl,
                    el_w[l], el_b[l], agg, N_NODES_C);
            else
                gine_agg_kernel<128, false><<<(N_NODES_C + 7) / 8, 256, 0, stream>>>(
                    hin, edge_attr, ea_perm, perm_src, perm_eid, rowstart, incl,
                    el_w[l], el_b[l], agg, N_NODES_C);
            node_kernel<128><<<N_NODES_C / 32, 256, 0, stream>>>(
                hin, agg, c_w1[l], c_b1[l], c_g[l], c_bt[l], c_w2[l], c_b2[l],
                h, N_NODES_C);
        }
    }

    // ---- pool + output MLP ----
    pool_kernel<<<N_GRAPHS_C, 256, 0, stream>>>(h, batch, o_w1, o_b1, o_w2, o_b2,
                                                (float*)d_out, N_NODES_C);
}

// Round 6
// 1163.169 us; speedup vs baseline: 2.3503x; 1.1063x over previous
//
#include <hip/hip_runtime.h>
#include <hip/hip_fp16.h>
#include <cstdint>
#include <cstddef>

#define N_NODES_C  100000
#define N_EDGES_C  1600000
#define N_GRAPHS_C 256
#define HID_C      128
// 1/sqrt(1+1e-5)
#define BN_SCALE_C 0.9999950000374997f

#define SCAN_B 1024
#define SCAN_NB ((N_NODES_C + SCAN_B - 1) / SCAN_B)   // 98

struct __align__(16) H8 { __half2 v[4]; };   // 8 fp16 = 16 B

// ---------------------------------------------------------------------------
// CSR build: histogram of dst, inclusive scan, scatter edge ids.
// ---------------------------------------------------------------------------
__global__ __launch_bounds__(256) void hist_kernel(
    const int* __restrict__ dst, int* __restrict__ counts, int n_edges)
{
    int e = blockIdx.x * 256 + threadIdx.x;
    if (e < n_edges) atomicAdd(&counts[dst[e]], 1);
}

__global__ __launch_bounds__(SCAN_B) void scan1_kernel(
    const int* __restrict__ counts, int* __restrict__ incl,
    int* __restrict__ blocksums, int n)
{
    __shared__ int sdata[SCAN_B];
    const int lid = threadIdx.x;
    const int i = blockIdx.x * SCAN_B + lid;
    sdata[lid] = (i < n) ? counts[i] : 0;
    __syncthreads();
#pragma unroll
    for (int off = 1; off < SCAN_B; off <<= 1) {
        int t = (lid >= off) ? sdata[lid - off] : 0;
        __syncthreads();
        sdata[lid] += t;
        __syncthreads();
    }
    if (i < n) incl[i] = sdata[lid];
    if (lid == SCAN_B - 1) blocksums[blockIdx.x] = sdata[lid];
}

__global__ void scan2_kernel(const int* __restrict__ blocksums,
                             int* __restrict__ blockoffs, int nb)
{
    if (threadIdx.x == 0 && blockIdx.x == 0) {
        int off = 0;
        for (int b = 0; b < nb; ++b) { blockoffs[b] = off; off += blocksums[b]; }
    }
}

__global__ __launch_bounds__(SCAN_B) void scan3_kernel(
    int* __restrict__ incl, const int* __restrict__ blockoffs, int n)
{
    const int i = blockIdx.x * SCAN_B + threadIdx.x;
    if (i < n) incl[i] += blockoffs[blockIdx.x];
}

__global__ __launch_bounds__(256) void initrows_kernel(
    const int* __restrict__ incl, const int* __restrict__ counts,
    int* __restrict__ rowstart, int* __restrict__ cursor, int n)
{
    const int i = blockIdx.x * 256 + threadIdx.x;
    if (i < n) {
        const int rs = incl[i] - counts[i];
        rowstart[i] = rs;
        cursor[i]   = rs;
    }
}

__global__ __launch_bounds__(256) void scatter_kernel(
    const int* __restrict__ src, const int* __restrict__ dst,
    int* __restrict__ cursor, int* __restrict__ perm_src,
    int* __restrict__ perm_eid, int n_edges)
{
    const int e = blockIdx.x * 256 + threadIdx.x;
    if (e < n_edges) {
        const int pos = atomicAdd(&cursor[dst[e]], 1);
        perm_src[pos] = src[e];
        perm_eid[pos] = e;
    }
}

// Gather edge_attr rows into CSR order AND convert to fp16 pairs:
// ea_f16[j][2k..2k+1] = {ea[2k], ea[2k+1]}. 32 B/row -> halved stream,
// conversion paid once for all 3 layers.
__global__ __launch_bounds__(256) void permute_ea_f16_kernel(
    const float* __restrict__ edge_attr, const int* __restrict__ perm_eid,
    __half* __restrict__ ea_f16, int n_edges)
{
    const int j = blockIdx.x * 256 + threadIdx.x;
    if (j >= n_edges) return;
    const int eid = perm_eid[j];
    const float4* p = (const float4*)(edge_attr + (size_t)eid * 16);
    const float4 q0 = p[0], q1 = p[1], q2 = p[2], q3 = p[3];
    H8 a, b;
    a.v[0] = __floats2half2_rn(q0.x, q0.y);
    a.v[1] = __floats2half2_rn(q0.z, q0.w);
    a.v[2] = __floats2half2_rn(q1.x, q1.y);
    a.v[3] = __floats2half2_rn(q1.z, q1.w);
    b.v[0] = __floats2half2_rn(q2.x, q2.y);
    b.v[1] = __floats2half2_rn(q2.z, q2.w);
    b.v[2] = __floats2half2_rn(q3.x, q3.y);
    b.v[3] = __floats2half2_rn(q3.z, q3.w);
    H8* o = (H8*)(ea_f16 + (size_t)j * 16);
    o[0] = a;
    o[1] = b;
}

// ---------------------------------------------------------------------------
// CSR aggregate, quad-per-lane + packed-fp16 edge MLP.
// Lane owns 4 consecutive features; ew pair-columns as __half2 (32 VGPRs);
// per edge: 2 VMEM (ea row) + 1 VMEM (h dwordx4) + 32 v_pk_fma_f16.
// Unroll x2 keeps 2 gather chains in flight.
// ---------------------------------------------------------------------------
__device__ __forceinline__ float4 eamlp_f16(const H8* __restrict__ p,
                                            const __half2 (*ew2)[4],
                                            const float4 ebv)
{
    const H8 a = p[0], b = p[1];
    __half2 c0 = {0.f, 0.f}, c1 = {0.f, 0.f}, c2 = {0.f, 0.f}, c3 = {0.f, 0.f};
#pragma unroll
    for (int k2 = 0; k2 < 4; ++k2) {
        c0 = __hfma2(a.v[k2], ew2[k2][0], c0);
        c1 = __hfma2(a.v[k2], ew2[k2][1], c1);
        c2 = __hfma2(a.v[k2], ew2[k2][2], c2);
        c3 = __hfma2(a.v[k2], ew2[k2][3], c3);
    }
#pragma unroll
    for (int k2 = 0; k2 < 4; ++k2) {
        c0 = __hfma2(b.v[k2], ew2[4 + k2][0], c0);
        c1 = __hfma2(b.v[k2], ew2[4 + k2][1], c1);
        c2 = __hfma2(b.v[k2], ew2[4 + k2][2], c2);
        c3 = __hfma2(b.v[k2], ew2[4 + k2][3], c3);
    }
    float4 m;
    m.x = ebv.x + __low2float(c0) + __high2float(c0);
    m.y = ebv.y + __low2float(c1) + __high2float(c1);
    m.z = ebv.z + __low2float(c2) + __high2float(c2);
    m.w = ebv.w + __low2float(c3) + __high2float(c3);
    return m;
}

template<int DIN>
__global__ __launch_bounds__(256) void gine_agg_kernel(
    const float* __restrict__ h, const __half* __restrict__ ea_f16,
    const int* __restrict__ perm_src,
    const int* __restrict__ rowstart, const int* __restrict__ rowend,
    const float* __restrict__ ew, const float* __restrict__ eb,
    float* __restrict__ agg, int n_nodes)
{
    constexpr int NQ    = DIN / 4;     // feature quads per node: 32 / 16
    constexpr int SLOTS = 256 / NQ;    // nodes per block: 8 / 16
    const int fq   = threadIdx.x & (NQ - 1);
    const int slot = threadIdx.x / NQ;
    const int v = blockIdx.x * SLOTS + slot;
    if (v >= n_nodes) return;

    // ew pair-columns for this lane's 4 features: ew2[k2][fi] = {ew[2k2][f], ew[2k2+1][f]}
    __half2 ew2[8][4];
#pragma unroll
    for (int k2 = 0; k2 < 8; ++k2)
#pragma unroll
        for (int fi = 0; fi < 4; ++fi)
            ew2[k2][fi] = __floats2half2_rn(ew[(size_t)(2 * k2)     * DIN + fq * 4 + fi],
                                            ew[(size_t)(2 * k2 + 1) * DIN + fq * 4 + fi]);
    const float4 ebv = *(const float4*)(eb + fq * 4);

    const int s0 = rowstart[v];
    const int s1 = rowend[v];

    float4 acc = {0.f, 0.f, 0.f, 0.f};
    int j = s0;
    for (; j + 2 <= s1; j += 2) {
        const int sn0 = perm_src[j + 0];
        const int sn1 = perm_src[j + 1];
        const float4 hv0 = *(const float4*)(h + (size_t)sn0 * DIN + fq * 4);
        const float4 hv1 = *(const float4*)(h + (size_t)sn1 * DIN + fq * 4);
        const H8* p0 = (const H8*)(ea_f16 + (size_t)(j + 0) * 16);
        const H8* p1 = (const H8*)(ea_f16 + (size_t)(j + 1) * 16);
        const float4 m0 = eamlp_f16(p0, ew2, ebv);
        const float4 m1 = eamlp_f16(p1, ew2, ebv);
        acc.x += fmaxf(m0.x + hv0.x, 0.f) + fmaxf(m1.x + hv1.x, 0.f);
        acc.y += fmaxf(m0.y + hv0.y, 0.f) + fmaxf(m1.y + hv1.y, 0.f);
        acc.z += fmaxf(m0.z + hv0.z, 0.f) + fmaxf(m1.z + hv1.z, 0.f);
        acc.w += fmaxf(m0.w + hv0.w, 0.f) + fmaxf(m1.w + hv1.w, 0.f);
    }
    if (j < s1) {
        const int sn = perm_src[j];
        const float4 hv = *(const float4*)(h + (size_t)sn * DIN + fq * 4);
        const H8* p = (const H8*)(ea_f16 + (size_t)j * 16);
        const float4 m = eamlp_f16(p, ew2, ebv);
        acc.x += fmaxf(m.x + hv.x, 0.f);
        acc.y += fmaxf(m.y + hv.y, 0.f);
        acc.z += fmaxf(m.z + hv.z, 0.f);
        acc.w += fmaxf(m.w + hv.w, 0.f);
    }
    *(float4*)(agg + (size_t)v * DIN + fq * 4) = acc;
}

// ---------------------------------------------------------------------------
// Node kernel v3: natural-orientation LDS tiles (conflict-free). Unchanged.
// ---------------------------------------------------------------------------
#define OUT4(acc, a0, a1, a2, a3, wv)                                     \
    do {                                                                  \
        acc[0][0] = fmaf(a0, wv.x, acc[0][0]);                            \
        acc[0][1] = fmaf(a0, wv.y, acc[0][1]);                            \
        acc[0][2] = fmaf(a0, wv.z, acc[0][2]);                            \
        acc[0][3] = fmaf(a0, wv.w, acc[0][3]);                            \
        acc[1][0] = fmaf(a1, wv.x, acc[1][0]);                            \
        acc[1][1] = fmaf(a1, wv.y, acc[1][1]);                            \
        acc[1][2] = fmaf(a1, wv.z, acc[1][2]);                            \
        acc[1][3] = fmaf(a1, wv.w, acc[1][3]);                            \
        acc[2][0] = fmaf(a2, wv.x, acc[2][0]);                            \
        acc[2][1] = fmaf(a2, wv.y, acc[2][1]);                            \
        acc[2][2] = fmaf(a2, wv.z, acc[2][2]);                            \
        acc[2][3] = fmaf(a2, wv.w, acc[2][3]);                            \
        acc[3][0] = fmaf(a3, wv.x, acc[3][0]);                            \
        acc[3][1] = fmaf(a3, wv.y, acc[3][1]);                            \
        acc[3][2] = fmaf(a3, wv.z, acc[3][2]);                            \
        acc[3][3] = fmaf(a3, wv.w, acc[3][3]);                            \
    } while (0)

template<int DIN>
__global__ __launch_bounds__(256) void node_kernel(
    const float* __restrict__ h, const float* __restrict__ agg,
    const float* __restrict__ w1, const float* __restrict__ b1,
    const float* __restrict__ gm, const float* __restrict__ bt,
    const float* __restrict__ w2, const float* __restrict__ b2,
    float* __restrict__ hout, int n_nodes)
{
    constexpr int SX = DIN + 4;
    constexpr int ST = HID_C + 4;
    __shared__ float s_x[32][SX];
    __shared__ float s_t[32][ST];

    const int tid = threadIdx.x;
    const int fg = tid & 31;
    const int ng = tid >> 5;
    const int base = blockIdx.x * 32;

    constexpr int KQ = DIN / 4;
    for (int idx = tid; idx < 32 * KQ; idx += 256) {
        const int ni = idx / KQ;
        const int k4 = (idx - ni * KQ) * 4;
        const int node = base + ni;
        const float4 hv = *(const float4*)(h   + (size_t)node * DIN + k4);
        const float4 av = *(const float4*)(agg + (size_t)node * DIN + k4);
        float4 s; s.x = hv.x + av.x; s.y = hv.y + av.y;
        s.z = hv.z + av.z; s.w = hv.w + av.w;
        *(float4*)(&s_x[ni][k4]) = s;
    }
    __syncthreads();

    {
        const float4 b1v = *(const float4*)(b1 + fg * 4);
        float acc[4][4];
#pragma unroll
        for (int ni = 0; ni < 4; ++ni) {
            acc[ni][0] = b1v.x; acc[ni][1] = b1v.y;
            acc[ni][2] = b1v.z; acc[ni][3] = b1v.w;
        }
        for (int k = 0; k < DIN; k += 4) {
            const float4 x0 = *(const float4*)(&s_x[ng * 4 + 0][k]);
            const float4 x1 = *(const float4*)(&s_x[ng * 4 + 1][k]);
            const float4 x2 = *(const float4*)(&s_x[ng * 4 + 2][k]);
            const float4 x3 = *(const float4*)(&s_x[ng * 4 + 3][k]);
            const float4 wa = *(const float4*)(w1 + (size_t)(k + 0) * HID_C + fg * 4);
            const float4 wb = *(const float4*)(w1 + (size_t)(k + 1) * HID_C + fg * 4);
            const float4 wc = *(const float4*)(w1 + (size_t)(k + 2) * HID_C + fg * 4);
            const float4 wd = *(const float4*)(w1 + (size_t)(k + 3) * HID_C + fg * 4);
            OUT4(acc, x0.x, x1.x, x2.x, x3.x, wa);
            OUT4(acc, x0.y, x1.y, x2.y, x3.y, wb);
            OUT4(acc, x0.z, x1.z, x2.z, x3.z, wc);
            OUT4(acc, x0.w, x1.w, x2.w, x3.w, wd);
        }
        const float4 gv  = *(const float4*)(gm + fg * 4);
        const float4 btv = *(const float4*)(bt + fg * 4);
#pragma unroll
        for (int ni = 0; ni < 4; ++ni) {
            float4 tv;
            tv.x = fmaxf(fmaf(acc[ni][0] * BN_SCALE_C, gv.x, btv.x), 0.f);
            tv.y = fmaxf(fmaf(acc[ni][1] * BN_SCALE_C, gv.y, btv.y), 0.f);
            tv.z = fmaxf(fmaf(acc[ni][2] * BN_SCALE_C, gv.z, btv.z), 0.f);
            tv.w = fmaxf(fmaf(acc[ni][3] * BN_SCALE_C, gv.w, btv.w), 0.f);
            *(float4*)(&s_t[ng * 4 + ni][fg * 4]) = tv;
        }
    }
    __syncthreads();

    {
        const float4 b2v = *(const float4*)(b2 + fg * 4);
        float acc[4][4];
#pragma unroll
        for (int ni = 0; ni < 4; ++ni) {
            acc[ni][0] = b2v.x; acc[ni][1] = b2v.y;
            acc[ni][2] = b2v.z; acc[ni][3] = b2v.w;
        }
        for (int k = 0; k < HID_C; k += 4) {
            const float4 x0 = *(const float4*)(&s_t[ng * 4 + 0][k]);
            const float4 x1 = *(const float4*)(&s_t[ng * 4 + 1][k]);
            const float4 x2 = *(const float4*)(&s_t[ng * 4 + 2][k]);
            const float4 x3 = *(const float4*)(&s_t[ng * 4 + 3][k]);
            const float4 wa = *(const float4*)(w2 + (size_t)(k + 0) * HID_C + fg * 4);
            const float4 wb = *(const float4*)(w2 + (size_t)(k + 1) * HID_C + fg * 4);
            const float4 wc = *(const float4*)(w2 + (size_t)(k + 2) * HID_C + fg * 4);
            const float4 wd = *(const float4*)(w2 + (size_t)(k + 3) * HID_C + fg * 4);
            OUT4(acc, x0.x, x1.x, x2.x, x3.x, wa);
            OUT4(acc, x0.y, x1.y, x2.y, x3.y, wb);
            OUT4(acc, x0.z, x1.z, x2.z, x3.z, wc);
            OUT4(acc, x0.w, x1.w, x2.w, x3.w, wd);
        }
#pragma unroll
        for (int ni = 0; ni < 4; ++ni) {
            const int node = base + ng * 4 + ni;
            float4 ov;
            ov.x = fmaxf(acc[ni][0], 0.f);
            ov.y = fmaxf(acc[ni][1], 0.f);
            ov.z = fmaxf(acc[ni][2], 0.f);
            ov.w = fmaxf(acc[ni][3], 0.f);
            *(float4*)(hout + (size_t)node * HID_C + fg * 4) = ov;
        }
    }
}

// ---------------------------------------------------------------------------
// Pool + output MLP (unchanged).
// ---------------------------------------------------------------------------
__global__ __launch_bounds__(256) void pool_kernel(
    const float* __restrict__ hfin, const int* __restrict__ batch,
    const float* __restrict__ w1, const float* __restrict__ b1,
    const float* __restrict__ w2, const float* __restrict__ b2,
    float* __restrict__ out, int n_nodes)
{
    const int gid = blockIdx.x;

    int lo = 0, hi = n_nodes;
    while (lo < hi) { int mid = (lo + hi) >> 1; if (batch[mid] < gid) lo = mid + 1; else hi = mid; }
    const int start = lo;
    hi = n_nodes;
    while (lo < hi) { int mid = (lo + hi) >> 1; if (batch[mid] < gid + 1) lo = mid + 1; else hi = mid; }
    const int end = lo;

    const int f = threadIdx.x & (HID_C - 1);
    const int half = threadIdx.x >> 7;

    float sum = 0.f;
    for (int n = start + half; n < end; n += 2)
        sum += hfin[(size_t)n * HID_C + f];

    __shared__ float s_sum[2][HID_C];
    __shared__ float s_p[HID_C];
    __shared__ float s_t[HID_C];
    s_sum[half][f] = sum;
    __syncthreads();

    if (threadIdx.x < HID_C) {
        const float cnt = (float)(end - start);
        s_p[f] = (s_sum[0][f] + s_sum[1][f]) / fmaxf(cnt, 1.f);
    }
    __syncthreads();

    if (threadIdx.x < HID_C) {
        float acc = b1[f];
        for (int k = 0; k < HID_C; ++k) acc = fmaf(s_p[k], w1[k * HID_C + f], acc);
        s_t[f] = fmaxf(acc, 0.f);
    }
    __syncthreads();

    if (threadIdx.x < HID_C) {
        float acc = b2[f];
        for (int k = 0; k < HID_C; ++k) acc = fmaf(s_t[k], w2[k * HID_C + f], acc);
        out[(size_t)gid * HID_C + f] = acc;
    }
}

// ---------------------------------------------------------------------------
extern "C" void kernel_launch(void* const* d_in, const int* in_sizes, int n_in,
                              void* d_out, int out_size, void* d_ws, size_t ws_size,
                              hipStream_t stream)
{
    const float* x         = (const float*)d_in[0];
    const float* edge_attr = (const float*)d_in[1];
    const int*   edge_index= (const int*)  d_in[2];
    const int*   batch     = (const int*)  d_in[3];
    const int*   src = edge_index;
    const int*   dst = edge_index + N_EDGES_C;

    const float* el_w[3] = {(const float*)d_in[4],  (const float*)d_in[12], (const float*)d_in[20]};
    const float* el_b[3] = {(const float*)d_in[5],  (const float*)d_in[13], (const float*)d_in[21]};
    const float* c_w1[3] = {(const float*)d_in[6],  (const float*)d_in[14], (const float*)d_in[22]};
    const float* c_b1[3] = {(const float*)d_in[7],  (const float*)d_in[15], (const float*)d_in[23]};
    const float* c_g [3] = {(const float*)d_in[8],  (const float*)d_in[16], (const float*)d_in[24]};
    const float* c_bt[3] = {(const float*)d_in[9],  (const float*)d_in[17], (const float*)d_in[25]};
    const float* c_w2[3] = {(const float*)d_in[10], (const float*)d_in[18], (const float*)d_in[26]};
    const float* c_b2[3] = {(const float*)d_in[11], (const float*)d_in[19], (const float*)d_in[27]};
    const float* o_w1 = (const float*)d_in[28];
    const float* o_b1 = (const float*)d_in[29];
    const float* o_w2 = (const float*)d_in[30];
    const float* o_b2 = (const float*)d_in[31];

    // ---- workspace layout ----
    char* wsp = (char*)d_ws;
    size_t used = 0;
    auto alloc = [&](size_t bytes) { char* p = wsp + used; used += (bytes + 255) & ~(size_t)255; return p; };
    float* h        = (float*)alloc((size_t)N_NODES_C * HID_C * 4);
    float* agg      = (float*)alloc((size_t)N_NODES_C * HID_C * 4);
    int*   counts   = (int*)alloc((size_t)N_NODES_C * 4);
    int*   incl     = (int*)alloc((size_t)N_NODES_C * 4);
    int*   rowstart = (int*)alloc((size_t)N_NODES_C * 4);
    int*   cursor   = (int*)alloc((size_t)N_NODES_C * 4);
    int*   blocksums= (int*)alloc(128 * 4);
    int*   blockoffs= (int*)alloc(128 * 4);
    int*   perm_src = (int*)alloc((size_t)N_EDGES_C * 4);
    int*   perm_eid = (int*)alloc((size_t)N_EDGES_C * 4);
    __half* ea_f16  = (__half*)alloc((size_t)N_EDGES_C * 16 * 2);
    (void)ws_size;

    // ---- CSR build (once; reused by all 3 layers) ----
    hipMemsetAsync(counts, 0, (size_t)N_NODES_C * 4, stream);
    hist_kernel<<<(N_EDGES_C + 255) / 256, 256, 0, stream>>>(dst, counts, N_EDGES_C);
    scan1_kernel<<<SCAN_NB, SCAN_B, 0, stream>>>(counts, incl, blocksums, N_NODES_C);
    scan2_kernel<<<1, 64, 0, stream>>>(blocksums, blockoffs, SCAN_NB);
    scan3_kernel<<<SCAN_NB, SCAN_B, 0, stream>>>(incl, blockoffs, N_NODES_C);
    initrows_kernel<<<(N_NODES_C + 255) / 256, 256, 0, stream>>>(incl, counts, rowstart,
                                                                 cursor, N_NODES_C);
    scatter_kernel<<<(N_EDGES_C + 255) / 256, 256, 0, stream>>>(src, dst, cursor,
                                                                perm_src, perm_eid, N_EDGES_C);
    permute_ea_f16_kernel<<<(N_EDGES_C + 255) / 256, 256, 0, stream>>>(
        edge_attr, perm_eid, ea_f16, N_EDGES_C);

    // ---- 3 GINE layers ----
    for (int l = 0; l < 3; ++l) {
        const float* hin = (l == 0) ? x : h;
        if (l == 0) {
            gine_agg_kernel<64><<<(N_NODES_C + 15) / 16, 256, 0, stream>>>(
                hin, ea_f16, perm_src, rowstart, incl, el_w[0], el_b[0],
                agg, N_NODES_C);
            node_kernel<64><<<N_NODES_C / 32, 256, 0, stream>>>(
                hin, agg, c_w1[0], c_b1[0], c_g[0], c_bt[0], c_w2[0], c_b2[0],
                h, N_NODES_C);
        } else {
            gine_agg_kernel<128><<<(N_NODES_C + 7) / 8, 256, 0, stream>>>(
                hin, ea_f16, perm_src, rowstart, incl, el_w[l], el_b[l],
                agg, N_NODES_C);
            node_kernel<128><<<N_NODES_C / 32, 256, 0, stream>>>(
                hin, agg, c_w1[l], c_b1[l], c_g[l], c_bt[l], c_w2[l], c_b2[l],
                h, N_NODES_C);
        }
    }

    // ---- pool + output MLP ----
    pool_kernel<<<N_GRAPHS_C, 256, 0, stream>>>(h, batch, o_w1, o_b1, o_w2, o_b2,
                                                (float*)d_out, N_NODES_C);
}

// Round 7
// 1103.876 us; speedup vs baseline: 2.4766x; 1.0537x over previous
//
#include <hip/hip_runtime.h>
#include <hip/hip_fp16.h>
#include <cstdint>
#include <cstddef>

#define N_NODES_C  100000
#define N_EDGES_C  1600000
#define N_GRAPHS_C 256
#define HID_C      128
// 1/sqrt(1+1e-5)
#define BN_SCALE_C 0.9999950000374997f

#define SCAN_B 1024
#define SCAN_NB ((N_NODES_C + SCAN_B - 1) / SCAN_B)   // 98

typedef _Float16 h8 __attribute__((ext_vector_type(8)));
typedef _Float16 h4 __attribute__((ext_vector_type(4)));
typedef float    f4 __attribute__((ext_vector_type(4)));

struct __align__(16) H8 { __half2 v[4]; };   // 8 fp16 = 16 B
struct __align__(8)  Hq { __half2 a, b; };   // 4 fp16 = 8 B

// ---------------------------------------------------------------------------
// CSR build: histogram of dst, inclusive scan, scatter edge ids.
// ---------------------------------------------------------------------------
__global__ __launch_bounds__(256) void hist_kernel(
    const int* __restrict__ dst, int* __restrict__ counts, int n_edges)
{
    int e = blockIdx.x * 256 + threadIdx.x;
    if (e < n_edges) atomicAdd(&counts[dst[e]], 1);
}

__global__ __launch_bounds__(SCAN_B) void scan1_kernel(
    const int* __restrict__ counts, int* __restrict__ incl,
    int* __restrict__ blocksums, int n)
{
    __shared__ int sdata[SCAN_B];
    const int lid = threadIdx.x;
    const int i = blockIdx.x * SCAN_B + lid;
    sdata[lid] = (i < n) ? counts[i] : 0;
    __syncthreads();
#pragma unroll
    for (int off = 1; off < SCAN_B; off <<= 1) {
        int t = (lid >= off) ? sdata[lid - off] : 0;
        __syncthreads();
        sdata[lid] += t;
        __syncthreads();
    }
    if (i < n) incl[i] = sdata[lid];
    if (lid == SCAN_B - 1) blocksums[blockIdx.x] = sdata[lid];
}

__global__ void scan2_kernel(const int* __restrict__ blocksums,
                             int* __restrict__ blockoffs, int nb)
{
    if (threadIdx.x == 0 && blockIdx.x == 0) {
        int off = 0;
        for (int b = 0; b < nb; ++b) { blockoffs[b] = off; off += blocksums[b]; }
    }
}

__global__ __launch_bounds__(SCAN_B) void scan3_kernel(
    int* __restrict__ incl, const int* __restrict__ blockoffs, int n)
{
    const int i = blockIdx.x * SCAN_B + threadIdx.x;
    if (i < n) incl[i] += blockoffs[blockIdx.x];
}

__global__ __launch_bounds__(256) void initrows_kernel(
    const int* __restrict__ incl, const int* __restrict__ counts,
    int* __restrict__ rowstart, int* __restrict__ cursor, int n)
{
    const int i = blockIdx.x * 256 + threadIdx.x;
    if (i < n) {
        const int rs = incl[i] - counts[i];
        rowstart[i] = rs;
        cursor[i]   = rs;
    }
}

__global__ __launch_bounds__(256) void scatter_kernel(
    const int* __restrict__ src, const int* __restrict__ dst,
    int* __restrict__ cursor, int* __restrict__ perm_src,
    int* __restrict__ perm_eid, int n_edges)
{
    const int e = blockIdx.x * 256 + threadIdx.x;
    if (e < n_edges) {
        const int pos = atomicAdd(&cursor[dst[e]], 1);
        perm_src[pos] = src[e];
        perm_eid[pos] = e;
    }
}

// Gather edge_attr rows into CSR order AND convert to fp16 pairs.
__global__ __launch_bounds__(256) void permute_ea_f16_kernel(
    const float* __restrict__ edge_attr, const int* __restrict__ perm_eid,
    __half* __restrict__ ea_f16, int n_edges)
{
    const int j = blockIdx.x * 256 + threadIdx.x;
    if (j >= n_edges) return;
    const int eid = perm_eid[j];
    const float4* p = (const float4*)(edge_attr + (size_t)eid * 16);
    const float4 q0 = p[0], q1 = p[1], q2 = p[2], q3 = p[3];
    H8 a, b;
    a.v[0] = __floats2half2_rn(q0.x, q0.y);
    a.v[1] = __floats2half2_rn(q0.z, q0.w);
    a.v[2] = __floats2half2_rn(q1.x, q1.y);
    a.v[3] = __floats2half2_rn(q1.z, q1.w);
    b.v[0] = __floats2half2_rn(q2.x, q2.y);
    b.v[1] = __floats2half2_rn(q2.z, q2.w);
    b.v[2] = __floats2half2_rn(q3.x, q3.y);
    b.v[3] = __floats2half2_rn(q3.z, q3.w);
    H8* o = (H8*)(ea_f16 + (size_t)j * 16);
    o[0] = a;
    o[1] = b;
}

// Cast fp32 array -> f16 (vectorized by 4).
__global__ __launch_bounds__(256) void cast_f16_kernel(
    const float* __restrict__ in, _Float16* __restrict__ out, int n4)
{
    const int i = blockIdx.x * 256 + threadIdx.x;
    if (i >= n4) return;
    const float4 v = ((const float4*)in)[i];
    h4 o; o[0] = (_Float16)v.x; o[1] = (_Float16)v.y;
    o[2] = (_Float16)v.z; o[3] = (_Float16)v.w;
    *(h4*)(out + (size_t)i * 4) = o;
}

// Transpose + cast weights: wt[n][k] = (f16) w[k][n].  (tiny, one-time)
__global__ __launch_bounds__(256) void transpose_w_kernel(
    const float* __restrict__ w, _Float16* __restrict__ wt, int K, int N)
{
    const int i = blockIdx.x * 256 + threadIdx.x;
    if (i >= K * N) return;
    const int n = i / K;
    const int k = i - n * K;
    wt[(size_t)n * K + k] = (_Float16)w[(size_t)k * N + n];
}

// ---------------------------------------------------------------------------
// CSR aggregate, quad-per-lane + packed-fp16 edge MLP + f16 h-gather.
// Per edge per lane: 2 VMEM (ea) + 1 dwordx2 (h f16) + 32 v_pk_fma_f16.
// ---------------------------------------------------------------------------
__device__ __forceinline__ float4 eamlp_f16(const H8* __restrict__ p,
                                            const __half2 (*ew2)[4],
                                            const float4 ebv)
{
    const H8 a = p[0], b = p[1];
    __half2 c0 = {0.f, 0.f}, c1 = {0.f, 0.f}, c2 = {0.f, 0.f}, c3 = {0.f, 0.f};
#pragma unroll
    for (int k2 = 0; k2 < 4; ++k2) {
        c0 = __hfma2(a.v[k2], ew2[k2][0], c0);
        c1 = __hfma2(a.v[k2], ew2[k2][1], c1);
        c2 = __hfma2(a.v[k2], ew2[k2][2], c2);
        c3 = __hfma2(a.v[k2], ew2[k2][3], c3);
    }
#pragma unroll
    for (int k2 = 0; k2 < 4; ++k2) {
        c0 = __hfma2(b.v[k2], ew2[4 + k2][0], c0);
        c1 = __hfma2(b.v[k2], ew2[4 + k2][1], c1);
        c2 = __hfma2(b.v[k2], ew2[4 + k2][2], c2);
        c3 = __hfma2(b.v[k2], ew2[4 + k2][3], c3);
    }
    float4 m;
    m.x = ebv.x + __low2float(c0) + __high2float(c0);
    m.y = ebv.y + __low2float(c1) + __high2float(c1);
    m.z = ebv.z + __low2float(c2) + __high2float(c2);
    m.w = ebv.w + __low2float(c3) + __high2float(c3);
    return m;
}

template<int DIN>
__global__ __launch_bounds__(256) void gine_agg_kernel(
    const __half* __restrict__ h16, const __half* __restrict__ ea_f16,
    const int* __restrict__ perm_src,
    const int* __restrict__ rowstart, const int* __restrict__ rowend,
    const float* __restrict__ ew, const float* __restrict__ eb,
    float* __restrict__ agg, int n_nodes)
{
    constexpr int NQ    = DIN / 4;
    constexpr int SLOTS = 256 / NQ;
    const int fq   = threadIdx.x & (NQ - 1);
    const int slot = threadIdx.x / NQ;
    const int v = blockIdx.x * SLOTS + slot;
    if (v >= n_nodes) return;

    __half2 ew2[8][4];
#pragma unroll
    for (int k2 = 0; k2 < 8; ++k2)
#pragma unroll
        for (int fi = 0; fi < 4; ++fi)
            ew2[k2][fi] = __floats2half2_rn(ew[(size_t)(2 * k2)     * DIN + fq * 4 + fi],
                                            ew[(size_t)(2 * k2 + 1) * DIN + fq * 4 + fi]);
    const float4 ebv = *(const float4*)(eb + fq * 4);

    const int s0 = rowstart[v];
    const int s1 = rowend[v];

    float4 acc = {0.f, 0.f, 0.f, 0.f};
    int j = s0;
    for (; j + 2 <= s1; j += 2) {
        const int sn0 = perm_src[j + 0];
        const int sn1 = perm_src[j + 1];
        const Hq hq0 = *(const Hq*)(h16 + (size_t)sn0 * DIN + fq * 4);
        const Hq hq1 = *(const Hq*)(h16 + (size_t)sn1 * DIN + fq * 4);
        const H8* p0 = (const H8*)(ea_f16 + (size_t)(j + 0) * 16);
        const H8* p1 = (const H8*)(ea_f16 + (size_t)(j + 1) * 16);
        const float4 m0 = eamlp_f16(p0, ew2, ebv);
        const float4 m1 = eamlp_f16(p1, ew2, ebv);
        const float2 l0 = __half22float2(hq0.a), u0 = __half22float2(hq0.b);
        const float2 l1 = __half22float2(hq1.a), u1 = __half22float2(hq1.b);
        acc.x += fmaxf(m0.x + l0.x, 0.f) + fmaxf(m1.x + l1.x, 0.f);
        acc.y += fmaxf(m0.y + l0.y, 0.f) + fmaxf(m1.y + l1.y, 0.f);
        acc.z += fmaxf(m0.z + u0.x, 0.f) + fmaxf(m1.z + u1.x, 0.f);
        acc.w += fmaxf(m0.w + u0.y, 0.f) + fmaxf(m1.w + u1.y, 0.f);
    }
    if (j < s1) {
        const int sn = perm_src[j];
        const Hq hq = *(const Hq*)(h16 + (size_t)sn * DIN + fq * 4);
        const H8* p = (const H8*)(ea_f16 + (size_t)j * 16);
        const float4 m = eamlp_f16(p, ew2, ebv);
        const float2 l = __half22float2(hq.a), u = __half22float2(hq.b);
        acc.x += fmaxf(m.x + l.x, 0.f);
        acc.y += fmaxf(m.y + l.y, 0.f);
        acc.z += fmaxf(m.z + u.x, 0.f);
        acc.w += fmaxf(m.w + u.y, 0.f);
    }
    *(float4*)(agg + (size_t)v * DIN + fq * 4) = acc;
}

// ---------------------------------------------------------------------------
// Node kernel v4 (MFMA f16): block = 4 waves, 16 nodes per wave.
// mm1: A = f16(h+agg) tile (LDS, +8 pad), B = W1T f16 (global, L2-hot);
// BN+relu in f32 regs -> s_t f16 -> mm2 -> relu -> hout f32 + h16 mirror.
// A layout: A[m=lane&15][k=quad*8+j]; B[k][n]: n=lane&15, k=quad*8+j;
// C/D: col=lane&15, row=quad*4+reg (per cdna_hip_programming.md §3).
// ---------------------------------------------------------------------------
template<int DIN>
__global__ __launch_bounds__(256) void node_mfma_kernel(
    const float* __restrict__ h, const float* __restrict__ agg,
    const _Float16* __restrict__ w1t, const float* __restrict__ b1,
    const float* __restrict__ gm, const float* __restrict__ bt,
    const _Float16* __restrict__ w2t, const float* __restrict__ b2,
    float* __restrict__ hout, _Float16* __restrict__ h16out, int n_tiles)
{
    constexpr int SXP = DIN + 8;
    constexpr int STP = HID_C + 8;
    __shared__ _Float16 s_x[4][16][SXP];
    __shared__ _Float16 s_t[4][16][STP];

    const int w    = threadIdx.x >> 6;
    const int lane = threadIdx.x & 63;
    int tile = blockIdx.x * 4 + w;
    if (tile >= n_tiles) tile = n_tiles - 1;   // clamp: keep barriers uniform
    const int node0 = tile * 16;

    // ---- stage X = h + agg -> f16 LDS tile ----
    constexpr int KQ = DIN / 4;
    for (int it = lane; it < 16 * KQ; it += 64) {
        const int ni = it / KQ;
        const int k4 = (it - ni * KQ) * 4;
        const float4 hv = *(const float4*)(h   + (size_t)(node0 + ni) * DIN + k4);
        const float4 av = *(const float4*)(agg + (size_t)(node0 + ni) * DIN + k4);
        h4 o;
        o[0] = (_Float16)(hv.x + av.x);
        o[1] = (_Float16)(hv.y + av.y);
        o[2] = (_Float16)(hv.z + av.z);
        o[3] = (_Float16)(hv.w + av.w);
        *(h4*)&s_x[w][ni][k4] = o;
    }
    __syncthreads();

    const int ln   = lane & 15;
    const int quad = lane >> 4;

    // ---- mm1 + BN + relu -> s_t (f16) ----
#pragma unroll
    for (int nt = 0; nt < 8; ++nt) {
        const int col = nt * 16 + ln;
        const float bv = b1[col];
        f4 acc = {bv, bv, bv, bv};
#pragma unroll
        for (int ks = 0; ks < DIN / 32; ++ks) {
            const h8 af = *(const h8*)&s_x[w][ln][ks * 32 + quad * 8];
            const h8 bf = *(const h8*)(w1t + (size_t)col * DIN + ks * 32 + quad * 8);
            acc = __builtin_amdgcn_mfma_f32_16x16x32_f16(af, bf, acc, 0, 0, 0);
        }
        const float gv = gm[col], btv = bt[col];
#pragma unroll
        for (int r = 0; r < 4; ++r) {
            const float t = fmaxf(fmaf(acc[r] * BN_SCALE_C, gv, btv), 0.f);
            s_t[w][quad * 4 + r][col] = (_Float16)t;
        }
    }
    __syncthreads();

    // ---- mm2 + relu -> hout f32 + h16 mirror ----
#pragma unroll
    for (int nt = 0; nt < 8; ++nt) {
        const int col = nt * 16 + ln;
        const float bv = b2[col];
        f4 acc = {bv, bv, bv, bv};
#pragma unroll
        for (int ks = 0; ks < HID_C / 32; ++ks) {
            const h8 af = *(const h8*)&s_t[w][ln][ks * 32 + quad * 8];
            const h8 bf = *(const h8*)(w2t + (size_t)col * HID_C + ks * 32 + quad * 8);
            acc = __builtin_amdgcn_mfma_f32_16x16x32_f16(af, bf, acc, 0, 0, 0);
        }
#pragma unroll
        for (int r = 0; r < 4; ++r) {
            const int node = node0 + quad * 4 + r;
            const float v = fmaxf(acc[r], 0.f);
            hout[(size_t)node * HID_C + col] = v;
            h16out[(size_t)node * HID_C + col] = (_Float16)v;
        }
    }
}

// ---------------------------------------------------------------------------
// Pool + output MLP (unchanged).
// ---------------------------------------------------------------------------
__global__ __launch_bounds__(256) void pool_kernel(
    const float* __restrict__ hfin, const int* __restrict__ batch,
    const float* __restrict__ w1, const float* __restrict__ b1,
    const float* __restrict__ w2, const float* __restrict__ b2,
    float* __restrict__ out, int n_nodes)
{
    const int gid = blockIdx.x;

    int lo = 0, hi = n_nodes;
    while (lo < hi) { int mid = (lo + hi) >> 1; if (batch[mid] < gid) lo = mid + 1; else hi = mid; }
    const int start = lo;
    hi = n_nodes;
    while (lo < hi) { int mid = (lo + hi) >> 1; if (batch[mid] < gid + 1) lo = mid + 1; else hi = mid; }
    const int end = lo;

    const int f = threadIdx.x & (HID_C - 1);
    const int half = threadIdx.x >> 7;

    float sum = 0.f;
    for (int n = start + half; n < end; n += 2)
        sum += hfin[(size_t)n * HID_C + f];

    __shared__ float s_sum[2][HID_C];
    __shared__ float s_p[HID_C];
    __shared__ float s_t[HID_C];
    s_sum[half][f] = sum;
    __syncthreads();

    if (threadIdx.x < HID_C) {
        const float cnt = (float)(end - start);
        s_p[f] = (s_sum[0][f] + s_sum[1][f]) / fmaxf(cnt, 1.f);
    }
    __syncthreads();

    if (threadIdx.x < HID_C) {
        float acc = b1[f];
        for (int k = 0; k < HID_C; ++k) acc = fmaf(s_p[k], w1[k * HID_C + f], acc);
        s_t[f] = fmaxf(acc, 0.f);
    }
    __syncthreads();

    if (threadIdx.x < HID_C) {
        float acc = b2[f];
        for (int k = 0; k < HID_C; ++k) acc = fmaf(s_t[k], w2[k * HID_C + f], acc);
        out[(size_t)gid * HID_C + f] = acc;
    }
}

// ---------------------------------------------------------------------------
extern "C" void kernel_launch(void* const* d_in, const int* in_sizes, int n_in,
                              void* d_out, int out_size, void* d_ws, size_t ws_size,
                              hipStream_t stream)
{
    const float* x         = (const float*)d_in[0];
    const float* edge_attr = (const float*)d_in[1];
    const int*   edge_index= (const int*)  d_in[2];
    const int*   batch     = (const int*)  d_in[3];
    const int*   src = edge_index;
    const int*   dst = edge_index + N_EDGES_C;

    const float* el_w[3] = {(const float*)d_in[4],  (const float*)d_in[12], (const float*)d_in[20]};
    const float* el_b[3] = {(const float*)d_in[5],  (const float*)d_in[13], (const float*)d_in[21]};
    const float* c_w1[3] = {(const float*)d_in[6],  (const float*)d_in[14], (const float*)d_in[22]};
    const float* c_b1[3] = {(const float*)d_in[7],  (const float*)d_in[15], (const float*)d_in[23]};
    const float* c_g [3] = {(const float*)d_in[8],  (const float*)d_in[16], (const float*)d_in[24]};
    const float* c_bt[3] = {(const float*)d_in[9],  (const float*)d_in[17], (const float*)d_in[25]};
    const float* c_w2[3] = {(const float*)d_in[10], (const float*)d_in[18], (const float*)d_in[26]};
    const float* c_b2[3] = {(const float*)d_in[11], (const float*)d_in[19], (const float*)d_in[27]};
    const float* o_w1 = (const float*)d_in[28];
    const float* o_b1 = (const float*)d_in[29];
    const float* o_w2 = (const float*)d_in[30];
    const float* o_b2 = (const float*)d_in[31];

    // ---- workspace layout (~207 MB; round 3 proved ws >= 220 MB) ----
    char* wsp = (char*)d_ws;
    size_t used = 0;
    auto alloc = [&](size_t bytes) { char* p = wsp + used; used += (bytes + 255) & ~(size_t)255; return p; };
    float* h        = (float*)alloc((size_t)N_NODES_C * HID_C * 4);
    float* agg      = (float*)alloc((size_t)N_NODES_C * HID_C * 4);
    int*   counts   = (int*)alloc((size_t)N_NODES_C * 4);
    int*   incl     = (int*)alloc((size_t)N_NODES_C * 4);
    int*   rowstart = (int*)alloc((size_t)N_NODES_C * 4);
    int*   cursor   = (int*)alloc((size_t)N_NODES_C * 4);
    int*   blocksums= (int*)alloc(128 * 4);
    int*   blockoffs= (int*)alloc(128 * 4);
    int*   perm_src = (int*)alloc((size_t)N_EDGES_C * 4);
    int*   perm_eid = (int*)alloc((size_t)N_EDGES_C * 4);
    __half*    ea_f16 = (__half*)alloc((size_t)N_EDGES_C * 16 * 2);
    _Float16*  h_f16  = (_Float16*)alloc((size_t)N_NODES_C * HID_C * 2);
    _Float16*  x_f16  = (_Float16*)alloc((size_t)N_NODES_C * 64 * 2);
    _Float16*  w1t[3], *w2t[3];
    for (int l = 0; l < 3; ++l) {
        w1t[l] = (_Float16*)alloc((size_t)HID_C * HID_C * 2);
        w2t[l] = (_Float16*)alloc((size_t)HID_C * HID_C * 2);
    }
    (void)ws_size;

    // ---- CSR build (once; reused by all 3 layers) ----
    hipMemsetAsync(counts, 0, (size_t)N_NODES_C * 4, stream);
    hist_kernel<<<(N_EDGES_C + 255) / 256, 256, 0, stream>>>(dst, counts, N_EDGES_C);
    scan1_kernel<<<SCAN_NB, SCAN_B, 0, stream>>>(counts, incl, blocksums, N_NODES_C);
    scan2_kernel<<<1, 64, 0, stream>>>(blocksums, blockoffs, SCAN_NB);
    scan3_kernel<<<SCAN_NB, SCAN_B, 0, stream>>>(incl, blockoffs, N_NODES_C);
    initrows_kernel<<<(N_NODES_C + 255) / 256, 256, 0, stream>>>(incl, counts, rowstart,
                                                                 cursor, N_NODES_C);
    scatter_kernel<<<(N_EDGES_C + 255) / 256, 256, 0, stream>>>(src, dst, cursor,
                                                                perm_src, perm_eid, N_EDGES_C);
    permute_ea_f16_kernel<<<(N_EDGES_C + 255) / 256, 256, 0, stream>>>(
        edge_attr, perm_eid, ea_f16, N_EDGES_C);
    cast_f16_kernel<<<(N_NODES_C * 64 / 4 + 255) / 256, 256, 0, stream>>>(
        x, x_f16, N_NODES_C * 64 / 4);
    for (int l = 0; l < 3; ++l) {
        const int K1 = (l == 0) ? 64 : HID_C;
        transpose_w_kernel<<<(K1 * HID_C + 255) / 256, 256, 0, stream>>>(
            c_w1[l], w1t[l], K1, HID_C);
        transpose_w_kernel<<<(HID_C * HID_C + 255) / 256, 256, 0, stream>>>(
            c_w2[l], w2t[l], HID_C, HID_C);
    }

    const int n_tiles = N_NODES_C / 16;            // 6250
    const int nb_node = (n_tiles + 3) / 4;         // 1563

    // ---- 3 GINE layers ----
    for (int l = 0; l < 3; ++l) {
        if (l == 0) {
            gine_agg_kernel<64><<<(N_NODES_C + 15) / 16, 256, 0, stream>>>(
                (const __half*)x_f16, ea_f16, perm_src, rowstart, incl,
                el_w[0], el_b[0], agg, N_NODES_C);
            node_mfma_kernel<64><<<nb_node, 256, 0, stream>>>(
                x, agg, w1t[0], c_b1[0], c_g[0], c_bt[0], w2t[0], c_b2[0],
                h, h_f16, n_tiles);
        } else {
            gine_agg_kernel<128><<<(N_NODES_C + 7) / 8, 256, 0, stream>>>(
                (const __half*)h_f16, ea_f16, perm_src, rowstart, incl,
                el_w[l], el_b[l], agg, N_NODES_C);
            node_mfma_kernel<128><<<nb_node, 256, 0, stream>>>(
                h, agg, w1t[l], c_b1[l], c_g[l], c_bt[l], w2t[l], c_b2[l],
                h, h_f16, n_tiles);
        }
    }

    // ---- pool + output MLP ----
    pool_kernel<<<N_GRAPHS_C, 256, 0, stream>>>(h, batch, o_w1, o_b1, o_w2, o_b2,
                                                (float*)d_out, N_NODES_C);
}